// Round 6
// baseline (170.901 us; speedup 1.0000x reference)
//
#include <hip/hip_runtime.h>
#include <hip/hip_fp16.h>
#include <stdint.h>
#include <math.h>

#define B 4096
#define D 512
#define NIMG_SHIFT 3

#define BM 256
#define BN 256
#define BK 32              // f16 elems per K-tile
#define NKT (D / BK)       // 16 K-tiles
#define NCH (B / BN)       // 16 col chunks

typedef _Float16 f16x8 __attribute__((ext_vector_type(8)));
typedef float f32x4 __attribute__((ext_vector_type(4)));

#define LDSPTR(p) ((__attribute__((address_space(3))) void*)(p))
#define GLPTR(p)  ((const __attribute__((address_space(1))) void*)(p))

// -------- static device workspace (fully rewritten every call) ----
__device__ __half   Q2d[(size_t)B * 1024];   // [r][0:512]=hi*2048, [512:1024]=lo
__device__ __half   G2d[(size_t)B * 1024];
__device__ float    nqd[B], ngd[B], psd[B], spd[B];
__device__ uint32_t bKeyd[B * NCH];
__device__ float    bDnd[B * NCH];
__device__ float    mDnd[B * NCH];
__device__ float    partd[B / 16];

// ---------------- threefry2x32 ----------------
__host__ __device__ inline void tf2x32(uint32_t k0, uint32_t k1,
                                       uint32_t x0, uint32_t x1,
                                       uint32_t& y0, uint32_t& y1) {
  const uint32_t ks2 = k0 ^ k1 ^ 0x1BD11BDAu;
  uint32_t v0 = x0 + k0, v1 = x1 + k1;
#define RR(r) { v0 += v1; v1 = (v1 << (r)) | (v1 >> (32 - (r))); v1 ^= v0; }
  RR(13) RR(15) RR(26) RR(6)   v0 += k1;  v1 += ks2 + 1u;
  RR(17) RR(29) RR(16) RR(24)  v0 += ks2; v1 += k0 + 2u;
  RR(13) RR(15) RR(26) RR(6)   v0 += k0;  v1 += k1 + 3u;
  RR(17) RR(29) RR(16) RR(24)  v0 += k1;  v1 += ks2 + 4u;
  RR(13) RR(15) RR(26) RR(6)   v0 += ks2; v1 += k0 + 5u;
#undef RR
  y0 = v0; y1 = v1;
}

__device__ inline uint32_t draw_bits(uint32_t key0, uint32_t key1, uint32_t flat) {
  uint32_t y0, y1;
  tf2x32(key0, key1, 0u, flat, y0, y1);
  return y1;
}

__device__ inline float gumbel_from_bits(uint32_t bits) {
  float f = __uint_as_float((bits >> 9) | 0x3f800000u) - 1.0f;
  float u = (f == 0.0f) ? 1.17549435e-38f : f;
  return -logf(-logf(u));
}

// ------- Kernel 0: fused fp32 -> f16 hi/lo split (x2048) + row norms -------
__global__ __launch_bounds__(256) void cvtn_k(const float* __restrict__ Q,
                                              const float* __restrict__ G) {
  int gtid = blockIdx.x * 256 + threadIdx.x;
  int wave = gtid >> 6;
  int lane = gtid & 63;
  if (wave >= 2 * B) return;
  const int isG = wave >= B;
  const float* src = isG ? G : Q;
  __half* dst = isG ? G2d : Q2d;
  const int row = isG ? wave - B : wave;
  const float4* p = (const float4*)(src + (size_t)row * D);
  float ssq = 0.0f;
#pragma unroll
  for (int i = 0; i < 2; i++) {
    const int e = lane + 64 * i;       // float4 index within row, 0..127
    float4 v = p[e];
    const float* pv = (const float*)&v;
    __half hh[4] __attribute__((aligned(8)));
    __half ll[4] __attribute__((aligned(8)));
#pragma unroll
    for (int j = 0; j < 4; j++) {
      const float x = pv[j];
      ssq += x * x;
      const float xs = x * 2048.0f;
      const __half h = __float2half(xs);
      hh[j] = h;
      ll[j] = __float2half(xs - __half2float(h));
    }
    *(uint2*)(dst + (size_t)row * 1024 + e * 4) = *(const uint2*)hh;
    *(uint2*)(dst + (size_t)row * 1024 + 512 + e * 4) = *(const uint2*)ll;
  }
#pragma unroll
  for (int off = 32; off; off >>= 1) ssq += __shfl_xor(ssq, off, 64);
  if (lane == 0) { if (isG) ngd[row] = ssq; else nqd[row] = ssq; }
}

// ---------------- Kernel 2: positive categorical sampling ----------------
__global__ __launch_bounds__(256) void pos_k(const float* __restrict__ Q,
                                             const float* __restrict__ G,
                                             uint32_t kp0, uint32_t kp1) {
  __shared__ float Qs[8][D];
  __shared__ float Gs[8][D];
  __shared__ float dots[8][8];
  int t = threadIdx.x;
  int rbase = blockIdx.x * 8;
#pragma unroll
  for (int s = 0; s < 4; s++) {
    int idx = t + 256 * s;
    int rr = idx >> 7;
    int kk = idx & 127;
    ((float4*)&Qs[rr][0])[kk] = ((const float4*)(Q + (size_t)(rbase + rr) * D))[kk];
    ((float4*)&Gs[rr][0])[kk] = ((const float4*)(G + (size_t)(rbase + rr) * D))[kk];
  }
  __syncthreads();
  {
    int p = t >> 2;
    int part = t & 3;
    int i = p >> 3, j = p & 7;
    float s = 0.0f;
    int k0 = part * 128;
    for (int k = k0; k < k0 + 128; k++) s += Qs[i][k] * Gs[j][k];
    s += __shfl_xor(s, 1, 64);
    s += __shfl_xor(s, 2, 64);
    if (part == 0) dots[i][j] = s;
  }
  __syncthreads();
  if (t < 8) {
    int i = t;
    int r = rbase + i;
    float nqr = nqd[r];
    float best = -INFINITY;
    float bdp = 0.0f;
#pragma unroll
    for (int j = 0; j < 8; j++) {
      if (j == i) continue;
      int c = rbase + j;
      float dp = fmaxf(nqr + ngd[c] - 2.0f * dots[i][j], 1e-8f);
      uint32_t bits = draw_bits(kp0, kp1, (uint32_t)(r * B + c));
      float logit = logf(dp) + gumbel_from_bits(bits);
      if (logit > best) { best = logit; bdp = dp; }
    }
    psd[r] = bdp;
    spd[r] = sqrtf(bdp);
  }
}

// ---- Kernel 3: 256x256 8-wave, 4-phase/K-tile MFMA GEMM + neg reductions ----
// LDS per buffer (64KB): Ah@0, Al@16K, Bh@32K, Bl@48K; 2 buffers = 128KB.
// Raw s_barrier phases (no auto vmcnt drain); one vmcnt(0) per K-tile at ph3.
__global__ __launch_bounds__(512) void neg_k(uint32_t kn0, uint32_t kn1) {
  __shared__ char lds[131072] __attribute__((aligned(16)));
  const int t = threadIdx.x;
  const int l = t & 63;
  const int w = t >> 6;          // 0..7
  const int wr = w >> 2;         // 0..1
  const int wc = w & 3;          // 0..3
  const int lane16 = l & 15, g16 = l >> 4;
  const int r0 = blockIdx.y * BM;
  const int c0 = blockIdx.x * BN;

  f32x4 acc[8][4];
#pragma unroll
  for (int mi = 0; mi < 8; mi++)
#pragma unroll
    for (int nj = 0; nj < 4; nj++) acc[mi][nj] = (f32x4){0.f, 0.f, 0.f, 0.f};

  const char* qbase = (const char*)Q2d + (size_t)r0 * 2048;
  const char* gbase = (const char*)G2d + (size_t)c0 * 2048;

  // staging: per plane (16KB), thread covers 2 chunks of 16B
  const int li0 = t << 4;            // 0..8191
  const int li1 = li0 + 8192;        // 8192..16383
  const int aa0 = li0 ^ (((li0 >> 7) & 3) << 4);
  const int aa1 = li1 ^ (((li1 >> 7) & 3) << 4);
  const char* sQ0 = qbase + (size_t)(aa0 >> 6) * 2048 + (aa0 & 63);
  const char* sQ1 = qbase + (size_t)(aa1 >> 6) * 2048 + (aa1 & 63);
  const char* sG0 = gbase + (size_t)(aa0 >> 6) * 2048 + (aa0 & 63);
  const char* sG1 = gbase + (size_t)(aa1 >> 6) * 2048 + (aa1 & 63);

  // fragment read offsets (swizzled; involution on bits[5:4]^row[2:1])
  int offA[8], offB[4];
#pragma unroll
  for (int i = 0; i < 8; i++) {
    const int a = (wr * 128 + i * 16 + lane16) * 64 + g16 * 16;
    offA[i] = a ^ (((a >> 7) & 3) << 4);
  }
#pragma unroll
  for (int i = 0; i < 4; i++) {
    const int a = (wc * 64 + i * 16 + lane16) * 64 + g16 * 16;
    offB[i] = a ^ (((a >> 7) & 3) << 4);
  }

  f16x8 bh[4], bl[4];

#define GLDS(SRC, DOFF) __builtin_amdgcn_global_load_lds(GLPTR(SRC), LDSPTR(lds + (DOFF)), 16, 0, 0)

  // prologue: stage K-tile 0 into buf0, full drain
  GLDS(sQ0, li0);          GLDS(sQ0 + 1024, 16384 + li0);
  GLDS(sQ1, li1);          GLDS(sQ1 + 1024, 8192 + 16384 + li1 - 8192);
  GLDS(sG0, 32768 + li0);  GLDS(sG0 + 1024, 49152 + li0);
  GLDS(sG1, 32768 + li1);  GLDS(sG1 + 1024, 49152 + li1);
  sQ0 += 64; sQ1 += 64; sG0 += 64; sG1 += 64;
  asm volatile("s_waitcnt vmcnt(0)" ::: "memory");
  __syncthreads();

#define PHASE(CUR, P, STA, STB, VMW) do {                                                     \
    const char* lsrc = lds + (CUR) * 65536;                                                   \
    char* ld2 = lds + (((CUR) ^ 1)) * 65536;                                                  \
    f16x8 a_h0 = *(const f16x8*)(lsrc + offA[2 * (P)]);                                       \
    f16x8 a_h1 = *(const f16x8*)(lsrc + offA[2 * (P) + 1]);                                   \
    f16x8 a_l0 = *(const f16x8*)(lsrc + 16384 + offA[2 * (P)]);                               \
    f16x8 a_l1 = *(const f16x8*)(lsrc + 16384 + offA[2 * (P) + 1]);                           \
    if ((P) == 0) {                                                                           \
      _Pragma("unroll")                                                                       \
      for (int nj = 0; nj < 4; nj++) {                                                        \
        bh[nj] = *(const f16x8*)(lsrc + 32768 + offB[nj]);                                    \
        bl[nj] = *(const f16x8*)(lsrc + 49152 + offB[nj]);                                    \
      }                                                                                       \
    }                                                                                         \
    if (STA) {                                                                                \
      GLDS(sQ0, ((CUR)^1)*65536 + li0);         GLDS(sQ0 + 1024, ((CUR)^1)*65536 + 16384 + li0); \
      GLDS(sQ1, ((CUR)^1)*65536 + li1);         GLDS(sQ1 + 1024, ((CUR)^1)*65536 + 16384 + li1); \
    }                                                                                         \
    if (STB) {                                                                                \
      GLDS(sG0, ((CUR)^1)*65536 + 32768 + li0); GLDS(sG0 + 1024, ((CUR)^1)*65536 + 49152 + li0); \
      GLDS(sG1, ((CUR)^1)*65536 + 32768 + li1); GLDS(sG1 + 1024, ((CUR)^1)*65536 + 49152 + li1); \
      sQ0 += 64; sQ1 += 64; sG0 += 64; sG1 += 64;                                             \
    }                                                                                         \
    if (VMW) asm volatile("s_waitcnt vmcnt(0)" ::: "memory");                                 \
    asm volatile("" ::: "memory");                                                            \
    __builtin_amdgcn_s_barrier();                                                             \
    asm volatile("s_waitcnt lgkmcnt(0)" ::: "memory");                                        \
    __builtin_amdgcn_sched_barrier(0);                                                        \
    __builtin_amdgcn_s_setprio(1);                                                            \
    _Pragma("unroll")                                                                         \
    for (int nj = 0; nj < 4; nj++) {                                                          \
      acc[2*(P)][nj]   = __builtin_amdgcn_mfma_f32_16x16x32_f16(a_h0, bh[nj], acc[2*(P)][nj],   0,0,0); \
      acc[2*(P)][nj]   = __builtin_amdgcn_mfma_f32_16x16x32_f16(a_l0, bh[nj], acc[2*(P)][nj],   0,0,0); \
      acc[2*(P)][nj]   = __builtin_amdgcn_mfma_f32_16x16x32_f16(a_h0, bl[nj], acc[2*(P)][nj],   0,0,0); \
      acc[2*(P)+1][nj] = __builtin_amdgcn_mfma_f32_16x16x32_f16(a_h1, bh[nj], acc[2*(P)+1][nj], 0,0,0); \
      acc[2*(P)+1][nj] = __builtin_amdgcn_mfma_f32_16x16x32_f16(a_l1, bh[nj], acc[2*(P)+1][nj], 0,0,0); \
      acc[2*(P)+1][nj] = __builtin_amdgcn_mfma_f32_16x16x32_f16(a_h1, bl[nj], acc[2*(P)+1][nj], 0,0,0); \
    }                                                                                         \
    __builtin_amdgcn_s_setprio(0);                                                            \
    __builtin_amdgcn_sched_barrier(0);                                                        \
    asm volatile("" ::: "memory");                                                            \
    __builtin_amdgcn_s_barrier();                                                             \
  } while (0)

#pragma unroll 1
  for (int it = 0; it < NKT / 2; it++) {
    PHASE(0, 0, 1, 0, 0);
    PHASE(0, 1, 0, 1, 0);
    PHASE(0, 2, 0, 0, 0);
    PHASE(0, 3, 0, 0, 1);
    PHASE(1, 0, 1, 0, 0);
    PHASE(1, 1, 0, 1, 0);
    PHASE(1, 2, 0, 0, 0);
    PHASE(1, 3, 0, 0, 1);
  }
#undef PHASE
#undef GLDS
  __syncthreads();   // full drain (incl. stray last prefetch) before LDS reuse

  // epilogue partial arrays overlaid on LDS: [4 wc][256 rows] x 5
  uint32_t* pKey = (uint32_t*)lds;
  uint32_t* pC   = pKey + 1024;
  float*    pD   = (float*)(pC + 1024);
  float*    pM   = pD + 1024;
  uint32_t* pMC  = (uint32_t*)(pM + 1024);

  // distance + per-row reductions. acc holds r*2^22; -2r = -acc * 2^-21
#pragma unroll
  for (int mi = 0; mi < 8; mi++) {
#pragma unroll
    for (int q = 0; q < 4; q++) {
      const int rr = wr * 128 + mi * 16 + g16 * 4 + q;
      const int r = r0 + rr;
      const float nqv = nqd[r];
      const float thr = psd[r] + 1e-4f;
      const int rg = r >> NIMG_SHIFT;
      uint32_t bKey = 0u, bC = 0xFFFFFFFFu, mC = 0xFFFFFFFFu;
      float bD = 0.0f, mD = INFINITY;
#pragma unroll
      for (int nj = 0; nj < 4; nj++) {
        const int c = c0 + wc * 64 + nj * 16 + lane16;
        const float dv = fmaxf(nqv + ngd[c] - acc[mi][nj][q] * 4.76837158203125e-07f, 1e-8f);
        const float dn = ((c >> NIMG_SHIFT) == rg) ? 1e25f : dv;
        if (dn < mD || (dn == mD && (uint32_t)c < mC)) { mD = dn; mC = (uint32_t)c; }
        if (dn < thr) {
          const uint32_t bits = draw_bits(kn0, kn1, (uint32_t)(r * B + c));
          const uint32_t key = (bits >> 9) + 1u;
          if (key > bKey || (key == bKey && (uint32_t)c < bC)) { bKey = key; bC = (uint32_t)c; bD = dn; }
        }
      }
#pragma unroll
      for (int off = 8; off >= 1; off >>= 1) {
        const uint32_t kO = __shfl_xor(bKey, off, 64);
        const uint32_t cO = __shfl_xor(bC, off, 64);
        const float dO = __shfl_xor(bD, off, 64);
        if (kO > bKey || (kO == bKey && cO < bC)) { bKey = kO; bC = cO; bD = dO; }
        const float mdO = __shfl_xor(mD, off, 64);
        const uint32_t mcO = __shfl_xor(mC, off, 64);
        if (mdO < mD || (mdO == mD && mcO < mC)) { mD = mdO; mC = mcO; }
      }
      if (lane16 == 0) {
        const int idx = wc * 256 + rr;
        pKey[idx] = bKey; pC[idx] = bC; pD[idx] = bD; pM[idx] = mD; pMC[idx] = mC;
      }
    }
  }
  __syncthreads();
  if (t < 256) {
    uint32_t bk = 0u, bc = 0xFFFFFFFFu; float bd = 0.0f;
    float md = INFINITY; uint32_t mc = 0xFFFFFFFFu;
#pragma unroll
    for (int wcc = 0; wcc < 4; wcc++) {
      const int idx = wcc * 256 + t;
      const uint32_t k = pKey[idx];
      const uint32_t c = pC[idx];
      const float d = pD[idx];
      if (k > bk || (k == bk && k != 0u && c < bc)) { bk = k; bc = c; bd = d; }
      const float m = pM[idx];
      const uint32_t c2 = pMC[idx];
      if (m < md || (m == md && c2 < mc)) { md = m; mc = c2; }
    }
    const int p = (r0 + t) * NCH + blockIdx.x;
    bKeyd[p] = bk; bDnd[p] = bd; mDnd[p] = md;
  }
}

// ---------------- Kernel 4a: per-row chunk combine + softplus, block partial --
__global__ __launch_bounds__(256) void fin1_k() {
  __shared__ float red[16];
  const int t = threadIdx.x;
  const int lrow = t >> 4;              // 0..15 rows per block
  const int ch = t & 15;                // chunk index (NCH=16)
  const int r = blockIdx.x * 16 + lrow;
  const int p = r * NCH + ch;
  uint32_t bk = bKeyd[p];
  uint32_t bch = (uint32_t)ch;
  float bd = bDnd[p];
  float md = mDnd[p];
  uint32_t mch = (uint32_t)ch;
#pragma unroll
  for (int off = 8; off >= 1; off >>= 1) {
    const uint32_t kO = __shfl_xor(bk, off, 64);
    const uint32_t cO = __shfl_xor(bch, off, 64);
    const float dO = __shfl_xor(bd, off, 64);
    if (kO > bk || (kO == bk && cO < bch)) { bk = kO; bch = cO; bd = dO; }
    const float mO = __shfl_xor(md, off, 64);
    const uint32_t mcO = __shfl_xor(mch, off, 64);
    if (mO < md || (mO == md && mcO < mch)) { md = mO; mch = mcO; }
  }
  if (ch == 0) {
    const float dn = (bk != 0u) ? bd : md;
    const float x = 1e-4f + spd[r] - sqrtf(dn);
    red[lrow] = fmaxf(x, 0.0f) + log1pf(expf(-fabsf(x)));
  }
  __syncthreads();
  if (t == 0) {
    float s = 0.0f;
#pragma unroll
    for (int i = 0; i < 16; i++) s += red[i];
    partd[blockIdx.x] = s;
  }
}

// ---------------- Kernel 4b: sum 256 partials, mean ----------------
__global__ __launch_bounds__(256) void fin2_k(float* __restrict__ out) {
  __shared__ float red[256];
  const int t = threadIdx.x;
  red[t] = partd[t];
  __syncthreads();
#pragma unroll
  for (int s = 128; s; s >>= 1) {
    if (t < s) red[t] += red[t + s];
    __syncthreads();
  }
  if (t == 0) out[0] = red[0] * (1.0f / (float)B);
}

extern "C" void kernel_launch(void* const* d_in, const int* in_sizes, int n_in,
                              void* d_out, int out_size, void* d_ws, size_t ws_size,
                              hipStream_t stream) {
  (void)in_sizes; (void)n_in; (void)out_size; (void)d_ws; (void)ws_size;
  const float* Q = (const float*)d_in[0];
  const float* G = (const float*)d_in[1];
  float* out = (float*)d_out;

  uint32_t kp0, kp1, kn0, kn1;
  tf2x32(0u, 42u, 0u, 0u, kp0, kp1);
  tf2x32(0u, 42u, 0u, 1u, kn0, kn1);

  hipLaunchKernelGGL(cvtn_k, dim3(2 * B / 4), dim3(256), 0, stream, Q, G);
  hipLaunchKernelGGL(pos_k, dim3(B / 8), dim3(256), 0, stream, Q, G, kp0, kp1);
  hipLaunchKernelGGL(neg_k, dim3(B / BN, B / BM), dim3(512), 0, stream, kn0, kn1);
  hipLaunchKernelGGL(fin1_k, dim3(B / 16), dim3(256), 0, stream);
  hipLaunchKernelGGL(fin2_k, dim3(1), dim3(256), 0, stream, out);
}

// Round 7
// 170.800 us; speedup vs baseline: 1.0006x; 1.0006x over previous
//
#include <hip/hip_runtime.h>
#include <hip/hip_fp16.h>
#include <stdint.h>
#include <math.h>

#define B 4096
#define D 512
#define NIMG_SHIFT 3

#define BM 256
#define BN 256
#define BK 32              // f16 elems per K-tile
#define NKT (D / BK)       // 16 K-tiles
#define NCH (B / BN)       // 16 col chunks

typedef _Float16 f16x8 __attribute__((ext_vector_type(8)));
typedef float f32x4 __attribute__((ext_vector_type(4)));

#define LDSPTR(p) ((__attribute__((address_space(3))) void*)(p))
#define GLPTR(p)  ((const __attribute__((address_space(1))) void*)(p))

// -------- static device workspace (fully rewritten every call) ----
__device__ __half   Q2d[(size_t)B * 1024];   // [r][0:512]=hi*2048, [512:1024]=lo
__device__ __half   G2d[(size_t)B * 1024];
__device__ float    nqd[B], ngd[B], psd[B], spd[B];
__device__ uint32_t bKeyd[B * NCH];
__device__ float    bDnd[B * NCH];
__device__ float    mDnd[B * NCH];
__device__ float    partd[B / 16];

// ---------------- threefry2x32 ----------------
__host__ __device__ inline void tf2x32(uint32_t k0, uint32_t k1,
                                       uint32_t x0, uint32_t x1,
                                       uint32_t& y0, uint32_t& y1) {
  const uint32_t ks2 = k0 ^ k1 ^ 0x1BD11BDAu;
  uint32_t v0 = x0 + k0, v1 = x1 + k1;
#define RR(r) { v0 += v1; v1 = (v1 << (r)) | (v1 >> (32 - (r))); v1 ^= v0; }
  RR(13) RR(15) RR(26) RR(6)   v0 += k1;  v1 += ks2 + 1u;
  RR(17) RR(29) RR(16) RR(24)  v0 += ks2; v1 += k0 + 2u;
  RR(13) RR(15) RR(26) RR(6)   v0 += k0;  v1 += k1 + 3u;
  RR(17) RR(29) RR(16) RR(24)  v0 += k1;  v1 += ks2 + 4u;
  RR(13) RR(15) RR(26) RR(6)   v0 += ks2; v1 += k0 + 5u;
#undef RR
  y0 = v0; y1 = v1;
}

__device__ inline uint32_t draw_bits(uint32_t key0, uint32_t key1, uint32_t flat) {
  uint32_t y0, y1;
  tf2x32(key0, key1, 0u, flat, y0, y1);
  return y1;
}

__device__ inline float gumbel_from_bits(uint32_t bits) {
  float f = __uint_as_float((bits >> 9) | 0x3f800000u) - 1.0f;
  float u = (f == 0.0f) ? 1.17549435e-38f : f;
  return -logf(-logf(u));
}

// ------- Kernel 0: fused fp32 -> f16 hi/lo split (x2048) + row norms -------
__global__ __launch_bounds__(256) void cvtn_k(const float* __restrict__ Q,
                                              const float* __restrict__ G) {
  int gtid = blockIdx.x * 256 + threadIdx.x;
  int wave = gtid >> 6;
  int lane = gtid & 63;
  if (wave >= 2 * B) return;
  const int isG = wave >= B;
  const float* src = isG ? G : Q;
  __half* dst = isG ? G2d : Q2d;
  const int row = isG ? wave - B : wave;
  const float4* p = (const float4*)(src + (size_t)row * D);
  float ssq = 0.0f;
#pragma unroll
  for (int i = 0; i < 2; i++) {
    const int e = lane + 64 * i;       // float4 index within row, 0..127
    float4 v = p[e];
    const float* pv = (const float*)&v;
    __half hh[4] __attribute__((aligned(8)));
    __half ll[4] __attribute__((aligned(8)));
#pragma unroll
    for (int j = 0; j < 4; j++) {
      const float x = pv[j];
      ssq += x * x;
      const float xs = x * 2048.0f;
      const __half h = __float2half(xs);
      hh[j] = h;
      ll[j] = __float2half(xs - __half2float(h));
    }
    *(uint2*)(dst + (size_t)row * 1024 + e * 4) = *(const uint2*)hh;
    *(uint2*)(dst + (size_t)row * 1024 + 512 + e * 4) = *(const uint2*)ll;
  }
#pragma unroll
  for (int off = 32; off; off >>= 1) ssq += __shfl_xor(ssq, off, 64);
  if (lane == 0) { if (isG) ngd[row] = ssq; else nqd[row] = ssq; }
}

// ---------------- Kernel 2: positive categorical sampling ----------------
__global__ __launch_bounds__(256) void pos_k(const float* __restrict__ Q,
                                             const float* __restrict__ G,
                                             uint32_t kp0, uint32_t kp1) {
  __shared__ float Qs[8][D];
  __shared__ float Gs[8][D];
  __shared__ float dots[8][8];
  int t = threadIdx.x;
  int rbase = blockIdx.x * 8;
#pragma unroll
  for (int s = 0; s < 4; s++) {
    int idx = t + 256 * s;
    int rr = idx >> 7;
    int kk = idx & 127;
    ((float4*)&Qs[rr][0])[kk] = ((const float4*)(Q + (size_t)(rbase + rr) * D))[kk];
    ((float4*)&Gs[rr][0])[kk] = ((const float4*)(G + (size_t)(rbase + rr) * D))[kk];
  }
  __syncthreads();
  {
    int p = t >> 2;
    int part = t & 3;
    int i = p >> 3, j = p & 7;
    float s = 0.0f;
    int k0 = part * 128;
    for (int k = k0; k < k0 + 128; k++) s += Qs[i][k] * Gs[j][k];
    s += __shfl_xor(s, 1, 64);
    s += __shfl_xor(s, 2, 64);
    if (part == 0) dots[i][j] = s;
  }
  __syncthreads();
  if (t < 8) {
    int i = t;
    int r = rbase + i;
    float nqr = nqd[r];
    float best = -INFINITY;
    float bdp = 0.0f;
#pragma unroll
    for (int j = 0; j < 8; j++) {
      if (j == i) continue;
      int c = rbase + j;
      float dp = fmaxf(nqr + ngd[c] - 2.0f * dots[i][j], 1e-8f);
      uint32_t bits = draw_bits(kp0, kp1, (uint32_t)(r * B + c));
      float logit = logf(dp) + gumbel_from_bits(bits);
      if (logit > best) { best = logit; bdp = dp; }
    }
    psd[r] = bdp;
    spd[r] = sqrtf(bdp);
  }
}

// ---- Kernel 3: 256x256 8-wave, 4-phase/K-tile MFMA GEMM + neg reductions ----
// LDS per buffer (64KB): Ah@0, Al@16K, Bh@32K, Bl@48K; 2 buffers = 128KB.
// Raw s_barrier phases (no auto vmcnt drain); one vmcnt(0) per K-tile at ph3.
// B fragments re-read each phase (not persisted) to keep VGPR < 256: no spill.
__global__ __launch_bounds__(512, 2) void neg_k(uint32_t kn0, uint32_t kn1) {
  __shared__ char lds[131072] __attribute__((aligned(16)));
  const int t = threadIdx.x;
  const int l = t & 63;
  const int w = t >> 6;          // 0..7
  const int wr = w >> 2;         // 0..1
  const int wc = w & 3;          // 0..3
  const int lane16 = l & 15, g16 = l >> 4;
  const int r0 = blockIdx.y * BM;
  const int c0 = blockIdx.x * BN;

  f32x4 acc[8][4];
#pragma unroll
  for (int mi = 0; mi < 8; mi++)
#pragma unroll
    for (int nj = 0; nj < 4; nj++) acc[mi][nj] = (f32x4){0.f, 0.f, 0.f, 0.f};

  const char* qbase = (const char*)Q2d + (size_t)r0 * 2048;
  const char* gbase = (const char*)G2d + (size_t)c0 * 2048;

  // staging: per plane (16KB), thread covers 2 chunks of 16B
  const int li0 = t << 4;            // 0..8191
  const int li1 = li0 + 8192;        // 8192..16383
  const int aa0 = li0 ^ (((li0 >> 7) & 3) << 4);
  const int aa1 = li1 ^ (((li1 >> 7) & 3) << 4);
  const char* sQ0 = qbase + (size_t)(aa0 >> 6) * 2048 + (aa0 & 63);
  const char* sQ1 = qbase + (size_t)(aa1 >> 6) * 2048 + (aa1 & 63);
  const char* sG0 = gbase + (size_t)(aa0 >> 6) * 2048 + (aa0 & 63);
  const char* sG1 = gbase + (size_t)(aa1 >> 6) * 2048 + (aa1 & 63);

  // fragment read offsets (swizzled; involution on bits[5:4]^row[2:1])
  int offA[8], offB[4];
#pragma unroll
  for (int i = 0; i < 8; i++) {
    const int a = (wr * 128 + i * 16 + lane16) * 64 + g16 * 16;
    offA[i] = a ^ (((a >> 7) & 3) << 4);
  }
#pragma unroll
  for (int i = 0; i < 4; i++) {
    const int a = (wc * 64 + i * 16 + lane16) * 64 + g16 * 16;
    offB[i] = a ^ (((a >> 7) & 3) << 4);
  }

#define GLDS(SRC, DOFF) __builtin_amdgcn_global_load_lds(GLPTR(SRC), LDSPTR(lds + (DOFF)), 16, 0, 0)

  // prologue: stage K-tile 0 into buf0, full drain
  GLDS(sQ0, li0);          GLDS(sQ0 + 1024, 16384 + li0);
  GLDS(sQ1, li1);          GLDS(sQ1 + 1024, 16384 + li1);
  GLDS(sG0, 32768 + li0);  GLDS(sG0 + 1024, 49152 + li0);
  GLDS(sG1, 32768 + li1);  GLDS(sG1 + 1024, 49152 + li1);
  sQ0 += 64; sQ1 += 64; sG0 += 64; sG1 += 64;
  asm volatile("s_waitcnt vmcnt(0)" ::: "memory");
  __syncthreads();

#define PHASE(CUR, P, STA, STB, VMW) do {                                                     \
    const char* lsrc = lds + (CUR) * 65536;                                                   \
    f16x8 a_h0 = *(const f16x8*)(lsrc + offA[2 * (P)]);                                       \
    f16x8 a_h1 = *(const f16x8*)(lsrc + offA[2 * (P) + 1]);                                   \
    f16x8 a_l0 = *(const f16x8*)(lsrc + 16384 + offA[2 * (P)]);                               \
    f16x8 a_l1 = *(const f16x8*)(lsrc + 16384 + offA[2 * (P) + 1]);                           \
    f16x8 bh[4], bl[4];                                                                       \
    _Pragma("unroll")                                                                         \
    for (int nj = 0; nj < 4; nj++) {                                                          \
      bh[nj] = *(const f16x8*)(lsrc + 32768 + offB[nj]);                                      \
      bl[nj] = *(const f16x8*)(lsrc + 49152 + offB[nj]);                                      \
    }                                                                                         \
    if (STA) {                                                                                \
      GLDS(sQ0, ((CUR)^1)*65536 + li0);         GLDS(sQ0 + 1024, ((CUR)^1)*65536 + 16384 + li0); \
      GLDS(sQ1, ((CUR)^1)*65536 + li1);         GLDS(sQ1 + 1024, ((CUR)^1)*65536 + 16384 + li1); \
    }                                                                                         \
    if (STB) {                                                                                \
      GLDS(sG0, ((CUR)^1)*65536 + 32768 + li0); GLDS(sG0 + 1024, ((CUR)^1)*65536 + 49152 + li0); \
      GLDS(sG1, ((CUR)^1)*65536 + 32768 + li1); GLDS(sG1 + 1024, ((CUR)^1)*65536 + 49152 + li1); \
      sQ0 += 64; sQ1 += 64; sG0 += 64; sG1 += 64;                                             \
    }                                                                                         \
    if (VMW) asm volatile("s_waitcnt vmcnt(0)" ::: "memory");                                 \
    asm volatile("" ::: "memory");                                                            \
    __builtin_amdgcn_s_barrier();                                                             \
    asm volatile("s_waitcnt lgkmcnt(0)" ::: "memory");                                        \
    __builtin_amdgcn_sched_barrier(0);                                                        \
    __builtin_amdgcn_s_setprio(1);                                                            \
    _Pragma("unroll")                                                                         \
    for (int nj = 0; nj < 4; nj++) {                                                          \
      acc[2*(P)][nj]   = __builtin_amdgcn_mfma_f32_16x16x32_f16(a_h0, bh[nj], acc[2*(P)][nj],   0,0,0); \
      acc[2*(P)][nj]   = __builtin_amdgcn_mfma_f32_16x16x32_f16(a_l0, bh[nj], acc[2*(P)][nj],   0,0,0); \
      acc[2*(P)][nj]   = __builtin_amdgcn_mfma_f32_16x16x32_f16(a_h0, bl[nj], acc[2*(P)][nj],   0,0,0); \
      acc[2*(P)+1][nj] = __builtin_amdgcn_mfma_f32_16x16x32_f16(a_h1, bh[nj], acc[2*(P)+1][nj], 0,0,0); \
      acc[2*(P)+1][nj] = __builtin_amdgcn_mfma_f32_16x16x32_f16(a_l1, bh[nj], acc[2*(P)+1][nj], 0,0,0); \
      acc[2*(P)+1][nj] = __builtin_amdgcn_mfma_f32_16x16x32_f16(a_h1, bl[nj], acc[2*(P)+1][nj], 0,0,0); \
    }                                                                                         \
    __builtin_amdgcn_s_setprio(0);                                                            \
    __builtin_amdgcn_sched_barrier(0);                                                        \
    asm volatile("" ::: "memory");                                                            \
    __builtin_amdgcn_s_barrier();                                                             \
  } while (0)

#pragma unroll 1
  for (int it = 0; it < NKT / 2; it++) {
    PHASE(0, 0, 1, 0, 0);
    PHASE(0, 1, 0, 1, 0);
    PHASE(0, 2, 0, 0, 0);
    PHASE(0, 3, 0, 0, 1);
    PHASE(1, 0, 1, 0, 0);
    PHASE(1, 1, 0, 1, 0);
    PHASE(1, 2, 0, 0, 0);
    PHASE(1, 3, 0, 0, 1);
  }
#undef PHASE
#undef GLDS
  __syncthreads();   // full drain before LDS reuse

  // epilogue partial arrays overlaid on LDS: [4 wc][256 rows] x 5
  uint32_t* pKey = (uint32_t*)lds;
  uint32_t* pC   = pKey + 1024;
  float*    pD   = (float*)(pC + 1024);
  float*    pM   = pD + 1024;
  uint32_t* pMC  = (uint32_t*)(pM + 1024);

  // distance + per-row reductions. acc holds r*2^22; -2r = -acc * 2^-21
#pragma unroll
  for (int mi = 0; mi < 8; mi++) {
#pragma unroll
    for (int q = 0; q < 4; q++) {
      const int rr = wr * 128 + mi * 16 + g16 * 4 + q;
      const int r = r0 + rr;
      const float nqv = nqd[r];
      const float thr = psd[r] + 1e-4f;
      const int rg = r >> NIMG_SHIFT;
      uint32_t bKey = 0u, bC = 0xFFFFFFFFu, mC = 0xFFFFFFFFu;
      float bD = 0.0f, mD = INFINITY;
#pragma unroll
      for (int nj = 0; nj < 4; nj++) {
        const int c = c0 + wc * 64 + nj * 16 + lane16;
        const float dv = fmaxf(nqv + ngd[c] - acc[mi][nj][q] * 4.76837158203125e-07f, 1e-8f);
        const float dn = ((c >> NIMG_SHIFT) == rg) ? 1e25f : dv;
        if (dn < mD || (dn == mD && (uint32_t)c < mC)) { mD = dn; mC = (uint32_t)c; }
        if (dn < thr) {
          const uint32_t bits = draw_bits(kn0, kn1, (uint32_t)(r * B + c));
          const uint32_t key = (bits >> 9) + 1u;
          if (key > bKey || (key == bKey && (uint32_t)c < bC)) { bKey = key; bC = (uint32_t)c; bD = dn; }
        }
      }
#pragma unroll
      for (int off = 8; off >= 1; off >>= 1) {
        const uint32_t kO = __shfl_xor(bKey, off, 64);
        const uint32_t cO = __shfl_xor(bC, off, 64);
        const float dO = __shfl_xor(bD, off, 64);
        if (kO > bKey || (kO == bKey && cO < bC)) { bKey = kO; bC = cO; bD = dO; }
        const float mdO = __shfl_xor(mD, off, 64);
        const uint32_t mcO = __shfl_xor(mC, off, 64);
        if (mdO < mD || (mdO == mD && mcO < mC)) { mD = mdO; mC = mcO; }
      }
      if (lane16 == 0) {
        const int idx = wc * 256 + rr;
        pKey[idx] = bKey; pC[idx] = bC; pD[idx] = bD; pM[idx] = mD; pMC[idx] = mC;
      }
    }
  }
  __syncthreads();
  if (t < 256) {
    uint32_t bk = 0u, bc = 0xFFFFFFFFu; float bd = 0.0f;
    float md = INFINITY; uint32_t mc = 0xFFFFFFFFu;
#pragma unroll
    for (int wcc = 0; wcc < 4; wcc++) {
      const int idx = wcc * 256 + t;
      const uint32_t k = pKey[idx];
      const uint32_t c = pC[idx];
      const float d = pD[idx];
      if (k > bk || (k == bk && k != 0u && c < bc)) { bk = k; bc = c; bd = d; }
      const float m = pM[idx];
      const uint32_t c2 = pMC[idx];
      if (m < md || (m == md && c2 < mc)) { md = m; mc = c2; }
    }
    const int p = (r0 + t) * NCH + blockIdx.x;
    bKeyd[p] = bk; bDnd[p] = bd; mDnd[p] = md;
  }
}

// ---------------- Kernel 4a: per-row chunk combine + softplus, block partial --
__global__ __launch_bounds__(256) void fin1_k() {
  __shared__ float red[16];
  const int t = threadIdx.x;
  const int lrow = t >> 4;              // 0..15 rows per block
  const int ch = t & 15;                // chunk index (NCH=16)
  const int r = blockIdx.x * 16 + lrow;
  const int p = r * NCH + ch;
  uint32_t bk = bKeyd[p];
  uint32_t bch = (uint32_t)ch;
  float bd = bDnd[p];
  float md = mDnd[p];
  uint32_t mch = (uint32_t)ch;
#pragma unroll
  for (int off = 8; off >= 1; off >>= 1) {
    const uint32_t kO = __shfl_xor(bk, off, 64);
    const uint32_t cO = __shfl_xor(bch, off, 64);
    const float dO = __shfl_xor(bd, off, 64);
    if (kO > bk || (kO == bk && cO < bch)) { bk = kO; bch = cO; bd = dO; }
    const float mO = __shfl_xor(md, off, 64);
    const uint32_t mcO = __shfl_xor(mch, off, 64);
    if (mO < md || (mO == md && mcO < mch)) { md = mO; mch = mcO; }
  }
  if (ch == 0) {
    const float dn = (bk != 0u) ? bd : md;
    const float x = 1e-4f + spd[r] - sqrtf(dn);
    red[lrow] = fmaxf(x, 0.0f) + log1pf(expf(-fabsf(x)));
  }
  __syncthreads();
  if (t == 0) {
    float s = 0.0f;
#pragma unroll
    for (int i = 0; i < 16; i++) s += red[i];
    partd[blockIdx.x] = s;
  }
}

// ---------------- Kernel 4b: sum 256 partials, mean ----------------
__global__ __launch_bounds__(256) void fin2_k(float* __restrict__ out) {
  __shared__ float red[256];
  const int t = threadIdx.x;
  red[t] = partd[t];
  __syncthreads();
#pragma unroll
  for (int s = 128; s; s >>= 1) {
    if (t < s) red[t] += red[t + s];
    __syncthreads();
  }
  if (t == 0) out[0] = red[0] * (1.0f / (float)B);
}

extern "C" void kernel_launch(void* const* d_in, const int* in_sizes, int n_in,
                              void* d_out, int out_size, void* d_ws, size_t ws_size,
                              hipStream_t stream) {
  (void)in_sizes; (void)n_in; (void)out_size; (void)d_ws; (void)ws_size;
  const float* Q = (const float*)d_in[0];
  const float* G = (const float*)d_in[1];
  float* out = (float*)d_out;

  uint32_t kp0, kp1, kn0, kn1;
  tf2x32(0u, 42u, 0u, 0u, kp0, kp1);
  tf2x32(0u, 42u, 0u, 1u, kn0, kn1);

  hipLaunchKernelGGL(cvtn_k, dim3(2 * B / 4), dim3(256), 0, stream, Q, G);
  hipLaunchKernelGGL(pos_k, dim3(B / 8), dim3(256), 0, stream, Q, G, kp0, kp1);
  hipLaunchKernelGGL(neg_k, dim3(B / BN, B / BM), dim3(512), 0, stream, kn0, kn1);
  hipLaunchKernelGGL(fin1_k, dim3(B / 16), dim3(256), 0, stream);
  hipLaunchKernelGGL(fin2_k, dim3(1), dim3(256), 0, stream, out);
}

// Round 9
// 166.698 us; speedup vs baseline: 1.0252x; 1.0246x over previous
//
#include <hip/hip_runtime.h>
#include <hip/hip_fp16.h>
#include <stdint.h>
#include <math.h>

#define B 4096
#define D 512
#define NIMG_SHIFT 3

#define BM 128
#define BN 128
#define NKS 24             // virtual K = 1536 (3 segments of 512), BK=64
#define NCH (B / BN)       // 32 col chunks

typedef _Float16 f16x8 __attribute__((ext_vector_type(8)));
typedef float f32x4 __attribute__((ext_vector_type(4)));

#define LDSPTR(p) ((__attribute__((address_space(3))) void*)(p))
#define GLPTR(p)  ((const __attribute__((address_space(1))) void*)(p))

// -------- static device workspace (fully rewritten every call) ----
__device__ __half   Q2d[(size_t)B * 1024];   // [r][0:512]=hi*2048, [512:1024]=lo
__device__ __half   G2d[(size_t)B * 1024];
__device__ float    nqd[B], ngd[B], psd[B], spd[B];
__device__ uint32_t bKeyd[B * NCH];
__device__ float    bDnd[B * NCH];
__device__ float    mDnd[B * NCH];
__device__ float    partd[B / 8];

// ---------------- threefry2x32 ----------------
__host__ __device__ inline void tf2x32(uint32_t k0, uint32_t k1,
                                       uint32_t x0, uint32_t x1,
                                       uint32_t& y0, uint32_t& y1) {
  const uint32_t ks2 = k0 ^ k1 ^ 0x1BD11BDAu;
  uint32_t v0 = x0 + k0, v1 = x1 + k1;
#define RR(r) { v0 += v1; v1 = (v1 << (r)) | (v1 >> (32 - (r))); v1 ^= v0; }
  RR(13) RR(15) RR(26) RR(6)   v0 += k1;  v1 += ks2 + 1u;
  RR(17) RR(29) RR(16) RR(24)  v0 += ks2; v1 += k0 + 2u;
  RR(13) RR(15) RR(26) RR(6)   v0 += k0;  v1 += k1 + 3u;
  RR(17) RR(29) RR(16) RR(24)  v0 += k1;  v1 += ks2 + 4u;
  RR(13) RR(15) RR(26) RR(6)   v0 += ks2; v1 += k0 + 5u;
#undef RR
  y0 = v0; y1 = v1;
}

__device__ inline uint32_t draw_bits(uint32_t key0, uint32_t key1, uint32_t flat) {
  uint32_t y0, y1;
  tf2x32(key0, key1, 0u, flat, y0, y1);
  return y1;
}

__device__ inline float gumbel_from_bits(uint32_t bits) {
  float f = __uint_as_float((bits >> 9) | 0x3f800000u) - 1.0f;
  float u = (f == 0.0f) ? 1.17549435e-38f : f;
  return -logf(-logf(u));
}

// ------- Kernel 0: fused fp32 -> f16 hi/lo split (x2048) + row norms -------
__global__ __launch_bounds__(256) void cvtn_k(const float* __restrict__ Q,
                                              const float* __restrict__ G) {
  int gtid = blockIdx.x * 256 + threadIdx.x;
  int wave = gtid >> 6;
  int lane = gtid & 63;
  if (wave >= 2 * B) return;
  const int isG = wave >= B;
  const float* src = isG ? G : Q;
  __half* dst = isG ? G2d : Q2d;
  const int row = isG ? wave - B : wave;
  const float4* p = (const float4*)(src + (size_t)row * D);
  float ssq = 0.0f;
#pragma unroll
  for (int i = 0; i < 2; i++) {
    const int e = lane + 64 * i;       // float4 index within row, 0..127
    float4 v = p[e];
    const float* pv = (const float*)&v;
    __half hh[4] __attribute__((aligned(8)));
    __half ll[4] __attribute__((aligned(8)));
#pragma unroll
    for (int j = 0; j < 4; j++) {
      const float x = pv[j];
      ssq += x * x;
      const float xs = x * 2048.0f;
      const __half h = __float2half(xs);
      hh[j] = h;
      ll[j] = __float2half(xs - __half2float(h));
    }
    *(uint2*)(dst + (size_t)row * 1024 + e * 4) = *(const uint2*)hh;
    *(uint2*)(dst + (size_t)row * 1024 + 512 + e * 4) = *(const uint2*)ll;
  }
#pragma unroll
  for (int off = 32; off; off >>= 1) ssq += __shfl_xor(ssq, off, 64);
  if (lane == 0) { if (isG) ngd[row] = ssq; else nqd[row] = ssq; }
}

// ---------------- Kernel 2: positive categorical sampling ----------------
__global__ __launch_bounds__(256) void pos_k(const float* __restrict__ Q,
                                             const float* __restrict__ G,
                                             uint32_t kp0, uint32_t kp1) {
  __shared__ float Qs[8][D];
  __shared__ float Gs[8][D];
  __shared__ float dots[8][8];
  int t = threadIdx.x;
  int rbase = blockIdx.x * 8;
#pragma unroll
  for (int s = 0; s < 4; s++) {
    int idx = t + 256 * s;
    int rr = idx >> 7;
    int kk = idx & 127;
    ((float4*)&Qs[rr][0])[kk] = ((const float4*)(Q + (size_t)(rbase + rr) * D))[kk];
    ((float4*)&Gs[rr][0])[kk] = ((const float4*)(G + (size_t)(rbase + rr) * D))[kk];
  }
  __syncthreads();
  {
    int p = t >> 2;
    int part = t & 3;
    int i = p >> 3, j = p & 7;
    float s = 0.0f;
    int k0 = part * 128;
    for (int k = k0; k < k0 + 128; k++) s += Qs[i][k] * Gs[j][k];
    s += __shfl_xor(s, 1, 64);
    s += __shfl_xor(s, 2, 64);
    if (part == 0) dots[i][j] = s;
  }
  __syncthreads();
  if (t < 8) {
    int i = t;
    int r = rbase + i;
    float nqr = nqd[r];
    float best = -INFINITY;
    float bdp = 0.0f;
#pragma unroll
    for (int j = 0; j < 8; j++) {
      if (j == i) continue;
      int c = rbase + j;
      float dp = fmaxf(nqr + ngd[c] - 2.0f * dots[i][j], 1e-8f);
      uint32_t bits = draw_bits(kp0, kp1, (uint32_t)(r * B + c));
      float logit = logf(dp) + gumbel_from_bits(bits);
      if (logit > best) { best = logit; bdp = dp; }
    }
    psd[r] = bdp;
    spd[r] = sqrtf(bdp);
  }
}

// ---- Kernel 3: virtual-K=1536 single-plane MFMA GEMM (m97 structure) ----
// r = qh*gh + ql*gh + qh*gl as 3 K-segments of 512; per K-step just a
// per-segment byte offset into the hi/lo global layout. LDS: A 16KB + B 16KB.
__global__ __launch_bounds__(256) void neg_k(uint32_t kn0, uint32_t kn1) {
  __shared__ char lds[32768] __attribute__((aligned(16)));
  const int t = threadIdx.x;
  const int l = t & 63;
  const int w = t >> 6;          // 0..3
  const int wr = w >> 1, wc = w & 1;
  const int lane16 = l & 15, g16 = l >> 4;
  const int r0 = blockIdx.y * BM;
  const int c0 = blockIdx.x * BN;

  f32x4 acc[4][4];
#pragma unroll
  for (int mi = 0; mi < 4; mi++)
#pragma unroll
    for (int nj = 0; nj < 4; nj++) acc[mi][nj] = (f32x4){0.f, 0.f, 0.f, 0.f};

  const char* qbase = (const char*)Q2d + (size_t)r0 * 2048;
  const char* gbase = (const char*)G2d + (size_t)c0 * 2048;

  // staging: linear LDS dest li[s]; logical (row,col) from inverse swizzle.
  // swizzle: byte ^= ((row&7)<<4), row = byte>>7 (128B rows) — involution.
  int li[4], rc[4];
#pragma unroll
  for (int s = 0; s < 4; s++) {
    li[s] = t * 16 + s * 4096;
    const int aa = li[s] ^ (((li[s] >> 7) & 7) << 4);
    rc[s] = (aa >> 7) * 2048 + (aa & 127);   // global row byte-offset + col
  }

  // fragment read offsets (swizzled). kk=1 is logical +64 (bit 6); since the
  // swizzle XOR covers bits 4-6, f(a+64) = f(a) ^ 64 (XOR, NOT add — add
  // carries into the row field when f(a) bit6=1: the round-8 bug).
  int offA[4], offA2[4], offB[4], offB2[4];
#pragma unroll
  for (int i = 0; i < 4; i++) {
    const int a = (wr * 64 + i * 16 + lane16) * 128 + g16 * 16;
    offA[i] = a ^ (((a >> 7) & 7) << 4);
    offA2[i] = offA[i] ^ 64;
    const int b = (wc * 64 + i * 16 + lane16) * 128 + g16 * 16;
    offB[i] = b ^ (((b >> 7) & 7) << 4);
    offB2[i] = offB[i] ^ 64;
  }

#define GLDS(SRC, DOFF) __builtin_amdgcn_global_load_lds(GLPTR(SRC), LDSPTR(lds + (DOFF)), 16, 0, 0)

#pragma unroll 1
  for (int ks = 0; ks < NKS; ks++) {
    const int seg = ks >> 3;
    const int inner = (ks & 7) * 128;
    const int aoff = (seg == 1 ? 1024 : 0) + inner;   // A: qh, ql, qh
    const int boff = (seg == 2 ? 1024 : 0) + inner;   // B: gh, gh, gl
    __syncthreads();
#pragma unroll
    for (int s = 0; s < 4; s++) {
      GLDS(qbase + rc[s] + aoff, li[s]);
      GLDS(gbase + rc[s] + boff, 16384 + li[s]);
    }
    __syncthreads();

    f16x8 av[4][2], bv[4][2];
#pragma unroll
    for (int i = 0; i < 4; i++) {
      av[i][0] = *(const f16x8*)(lds + offA[i]);
      av[i][1] = *(const f16x8*)(lds + offA2[i]);
      bv[i][0] = *(const f16x8*)(lds + 16384 + offB[i]);
      bv[i][1] = *(const f16x8*)(lds + 16384 + offB2[i]);
    }
#pragma unroll
    for (int kk = 0; kk < 2; kk++)
#pragma unroll
      for (int nj = 0; nj < 4; nj++)
#pragma unroll
        for (int mi = 0; mi < 4; mi++)
          acc[mi][nj] = __builtin_amdgcn_mfma_f32_16x16x32_f16(av[mi][kk], bv[nj][kk], acc[mi][nj], 0, 0, 0);
  }
#undef GLDS
  __syncthreads();

  // epilogue partial arrays overlaid on LDS
  uint32_t* pKey = (uint32_t*)lds;
  uint32_t* pC   = pKey + 256;
  float*    pD   = (float*)(pC + 256);
  float*    pM   = pD + 256;
  uint32_t* pMC  = (uint32_t*)(pM + 256);

  // distance + per-row reductions. acc holds r*2^22; -2r = -acc * 2^-21
#pragma unroll
  for (int mi = 0; mi < 4; mi++) {
#pragma unroll
    for (int q = 0; q < 4; q++) {
      const int rr = wr * 64 + mi * 16 + g16 * 4 + q;
      const int r = r0 + rr;
      const float nqv = nqd[r];
      const float thr = psd[r] + 1e-4f;
      const int rg = r >> NIMG_SHIFT;
      uint32_t bKey = 0u, bC = 0xFFFFFFFFu, mC = 0xFFFFFFFFu;
      float bD = 0.0f, mD = INFINITY;
#pragma unroll
      for (int nj = 0; nj < 4; nj++) {
        const int c = c0 + wc * 64 + nj * 16 + lane16;
        const float dv = fmaxf(nqv + ngd[c] - acc[mi][nj][q] * 4.76837158203125e-07f, 1e-8f);
        const float dn = ((c >> NIMG_SHIFT) == rg) ? 1e25f : dv;
        if (dn < mD || (dn == mD && (uint32_t)c < mC)) { mD = dn; mC = (uint32_t)c; }
        if (dn < thr) {
          const uint32_t bits = draw_bits(kn0, kn1, (uint32_t)(r * B + c));
          const uint32_t key = (bits >> 9) + 1u;
          if (key > bKey || (key == bKey && (uint32_t)c < bC)) { bKey = key; bC = (uint32_t)c; bD = dn; }
        }
      }
#pragma unroll
      for (int off = 8; off >= 1; off >>= 1) {
        const uint32_t kO = __shfl_xor(bKey, off, 64);
        const uint32_t cO = __shfl_xor(bC, off, 64);
        const float dO = __shfl_xor(bD, off, 64);
        if (kO > bKey || (kO == bKey && cO < bC)) { bKey = kO; bC = cO; bD = dO; }
        const float mdO = __shfl_xor(mD, off, 64);
        const uint32_t mcO = __shfl_xor(mC, off, 64);
        if (mdO < mD || (mdO == mD && mcO < mC)) { mD = mdO; mC = mcO; }
      }
      if (lane16 == 0) {
        const int idx = wc * 128 + rr;
        pKey[idx] = bKey; pC[idx] = bC; pD[idx] = bD; pM[idx] = mD; pMC[idx] = mC;
      }
    }
  }
  __syncthreads();
  if (t < 128) {
    const int i0 = t, i1 = t + 128;
    const uint32_t k0 = pKey[i0], k1 = pKey[i1];
    const uint32_t c0v = pC[i0], c1v = pC[i1];
    const float d0 = pD[i0], d1 = pD[i1];
    uint32_t bk; float bd;
    if (k1 > k0 || (k1 == k0 && k1 != 0u && c1v < c0v)) { bk = k1; bd = d1; }
    else { bk = k0; bd = d0; }
    const float m0 = pM[i0], m1 = pM[i1];
    const uint32_t mc0 = pMC[i0], mc1 = pMC[i1];
    const float md = (m1 < m0 || (m1 == m0 && mc1 < mc0)) ? m1 : m0;
    const int p = (r0 + t) * NCH + blockIdx.x;
    bKeyd[p] = bk; bDnd[p] = bd; mDnd[p] = md;
  }
}

// ---------------- Kernel 4a: per-row chunk combine + softplus, block partial --
__global__ __launch_bounds__(256) void fin1_k() {
  __shared__ float red[8];
  const int t = threadIdx.x;
  const int lrow = t >> 5;              // 0..7 rows per block
  const int ch = t & 31;                // chunk index (NCH=32)
  const int r = blockIdx.x * 8 + lrow;
  const int p = r * NCH + ch;
  uint32_t bk = bKeyd[p];
  uint32_t bch = (uint32_t)ch;
  float bd = bDnd[p];
  float md = mDnd[p];
  uint32_t mch = (uint32_t)ch;
#pragma unroll
  for (int off = 16; off >= 1; off >>= 1) {
    const uint32_t kO = __shfl_xor(bk, off, 64);
    const uint32_t cO = __shfl_xor(bch, off, 64);
    const float dO = __shfl_xor(bd, off, 64);
    if (kO > bk || (kO == bk && cO < bch)) { bk = kO; bch = cO; bd = dO; }
    const float mO = __shfl_xor(md, off, 64);
    const uint32_t mcO = __shfl_xor(mch, off, 64);
    if (mO < md || (mO == md && mcO < mch)) { md = mO; mch = mcO; }
  }
  if (ch == 0) {
    const float dn = (bk != 0u) ? bd : md;
    const float x = 1e-4f + spd[r] - sqrtf(dn);
    red[lrow] = fmaxf(x, 0.0f) + log1pf(expf(-fabsf(x)));
  }
  __syncthreads();
  if (t == 0) {
    float s = 0.0f;
#pragma unroll
    for (int i = 0; i < 8; i++) s += red[i];
    partd[blockIdx.x] = s;
  }
}

// ---------------- Kernel 4b: sum 512 partials, mean ----------------
__global__ __launch_bounds__(256) void fin2_k(float* __restrict__ out) {
  __shared__ float red[256];
  const int t = threadIdx.x;
  red[t] = partd[t] + partd[t + 256];
  __syncthreads();
#pragma unroll
  for (int s = 128; s; s >>= 1) {
    if (t < s) red[t] += red[t + s];
    __syncthreads();
  }
  if (t == 0) out[0] = red[0] * (1.0f / (float)B);
}

extern "C" void kernel_launch(void* const* d_in, const int* in_sizes, int n_in,
                              void* d_out, int out_size, void* d_ws, size_t ws_size,
                              hipStream_t stream) {
  (void)in_sizes; (void)n_in; (void)out_size; (void)d_ws; (void)ws_size;
  const float* Q = (const float*)d_in[0];
  const float* G = (const float*)d_in[1];
  float* out = (float*)d_out;

  uint32_t kp0, kp1, kn0, kn1;
  tf2x32(0u, 42u, 0u, 0u, kp0, kp1);
  tf2x32(0u, 42u, 0u, 1u, kn0, kn1);

  hipLaunchKernelGGL(cvtn_k, dim3(2 * B / 4), dim3(256), 0, stream, Q, G);
  hipLaunchKernelGGL(pos_k, dim3(B / 8), dim3(256), 0, stream, Q, G, kp0, kp1);
  hipLaunchKernelGGL(neg_k, dim3(B / BN, B / BM), dim3(256), 0, stream, kn0, kn1);
  hipLaunchKernelGGL(fin1_k, dim3(B / 8), dim3(256), 0, stream);
  hipLaunchKernelGGL(fin2_k, dim3(1), dim3(256), 0, stream, out);
}

// Round 10
// 122.751 us; speedup vs baseline: 1.3923x; 1.3580x over previous
//
#include <hip/hip_runtime.h>
#include <hip/hip_fp16.h>
#include <stdint.h>
#include <math.h>

#define B 4096
#define D 512
#define NIMG_SHIFT 3

#define BM 128
#define BN 128
#define NKS 8              // K = 512, BK = 64 f16 (128B)
#define NCH (B / BN)       // 32 col chunks

typedef _Float16 f16x8 __attribute__((ext_vector_type(8)));
typedef float f32x4 __attribute__((ext_vector_type(4)));

#define LDSPTR(p) ((__attribute__((address_space(3))) void*)(p))
#define GLPTR(p)  ((const __attribute__((address_space(1))) void*)(p))

// -------- static device workspace (fully rewritten every call) ----
__device__ __half   Q2h[(size_t)B * D];      // f16 copy of Q (unscaled)
__device__ __half   G2h[(size_t)B * D];
__device__ float    nqd[B], ngd[B], psd[B], spd[B];
__device__ uint32_t bKeyd[B * NCH];
__device__ float    bDnd[B * NCH];
__device__ float    mDnd[B * NCH];
__device__ float    partd[B / 8];

// ---------------- threefry2x32 ----------------
__host__ __device__ inline void tf2x32(uint32_t k0, uint32_t k1,
                                       uint32_t x0, uint32_t x1,
                                       uint32_t& y0, uint32_t& y1) {
  const uint32_t ks2 = k0 ^ k1 ^ 0x1BD11BDAu;
  uint32_t v0 = x0 + k0, v1 = x1 + k1;
#define RR(r) { v0 += v1; v1 = (v1 << (r)) | (v1 >> (32 - (r))); v1 ^= v0; }
  RR(13) RR(15) RR(26) RR(6)   v0 += k1;  v1 += ks2 + 1u;
  RR(17) RR(29) RR(16) RR(24)  v0 += ks2; v1 += k0 + 2u;
  RR(13) RR(15) RR(26) RR(6)   v0 += k0;  v1 += k1 + 3u;
  RR(17) RR(29) RR(16) RR(24)  v0 += k1;  v1 += ks2 + 4u;
  RR(13) RR(15) RR(26) RR(6)   v0 += ks2; v1 += k0 + 5u;
#undef RR
  y0 = v0; y1 = v1;
}

__device__ inline uint32_t draw_bits(uint32_t key0, uint32_t key1, uint32_t flat) {
  uint32_t y0, y1;
  tf2x32(key0, key1, 0u, flat, y0, y1);
  return y1;
}

__device__ inline float gumbel_from_bits(uint32_t bits) {
  float f = __uint_as_float((bits >> 9) | 0x3f800000u) - 1.0f;
  float u = (f == 0.0f) ? 1.17549435e-38f : f;
  return -logf(-logf(u));
}

// ------- Kernel 0: fp32 -> f16 copy + row sum-of-squares -------
__global__ __launch_bounds__(256) void cvtn_k(const float* __restrict__ Q,
                                              const float* __restrict__ G) {
  int gtid = blockIdx.x * 256 + threadIdx.x;
  int wave = gtid >> 6;
  int lane = gtid & 63;
  if (wave >= 2 * B) return;
  const int isG = wave >= B;
  const float* src = isG ? G : Q;
  __half* dst = isG ? G2h : Q2h;
  const int row = isG ? wave - B : wave;
  const float4* p = (const float4*)(src + (size_t)row * D);
  float ssq = 0.0f;
#pragma unroll
  for (int i = 0; i < 2; i++) {
    const int e = lane + 64 * i;       // float4 index within row, 0..127
    float4 v = p[e];
    const float* pv = (const float*)&v;
    __half hh[4] __attribute__((aligned(8)));
#pragma unroll
    for (int j = 0; j < 4; j++) {
      const float x = pv[j];
      ssq += x * x;
      hh[j] = __float2half(x);
    }
    *(uint2*)(dst + (size_t)row * D + e * 4) = *(const uint2*)hh;
  }
#pragma unroll
  for (int off = 32; off; off >>= 1) ssq += __shfl_xor(ssq, off, 64);
  if (lane == 0) { if (isG) ngd[row] = ssq; else nqd[row] = ssq; }
}

// ---------------- Kernel 2: positive categorical sampling ----------------
__global__ __launch_bounds__(256) void pos_k(const float* __restrict__ Q,
                                             const float* __restrict__ G,
                                             uint32_t kp0, uint32_t kp1) {
  __shared__ float Qs[8][D];
  __shared__ float Gs[8][D];
  __shared__ float dots[8][8];
  int t = threadIdx.x;
  int rbase = blockIdx.x * 8;
#pragma unroll
  for (int s = 0; s < 4; s++) {
    int idx = t + 256 * s;
    int rr = idx >> 7;
    int kk = idx & 127;
    ((float4*)&Qs[rr][0])[kk] = ((const float4*)(Q + (size_t)(rbase + rr) * D))[kk];
    ((float4*)&Gs[rr][0])[kk] = ((const float4*)(G + (size_t)(rbase + rr) * D))[kk];
  }
  __syncthreads();
  {
    int p = t >> 2;
    int part = t & 3;
    int i = p >> 3, j = p & 7;
    float s = 0.0f;
    int k0 = part * 128;
    for (int k = k0; k < k0 + 128; k++) s += Qs[i][k] * Gs[j][k];
    s += __shfl_xor(s, 1, 64);
    s += __shfl_xor(s, 2, 64);
    if (part == 0) dots[i][j] = s;
  }
  __syncthreads();
  if (t < 8) {
    int i = t;
    int r = rbase + i;
    float nqr = nqd[r];
    float best = -INFINITY;
    float bdp = 0.0f;
#pragma unroll
    for (int j = 0; j < 8; j++) {
      if (j == i) continue;
      int c = rbase + j;
      float dp = fmaxf(nqr + ngd[c] - 2.0f * dots[i][j], 1e-8f);
      uint32_t bits = draw_bits(kp0, kp1, (uint32_t)(r * B + c));
      float logit = logf(dp) + gumbel_from_bits(bits);
      if (logit > best) { best = logit; bdp = dp; }
    }
    psd[r] = bdp;
    spd[r] = sqrtf(bdp);
  }
}

// ---- Kernel 3: single-plane f16 MFMA GEMM (m97 structure) + reductions ----
// LDS: A [128 rows][128B] @0 (16KB), B @16384 (16KB). Single-buffered, 8 steps.
__global__ __launch_bounds__(256) void neg_k(uint32_t kn0, uint32_t kn1) {
  __shared__ char lds[32768] __attribute__((aligned(16)));
  const int t = threadIdx.x;
  const int l = t & 63;
  const int w = t >> 6;          // 0..3
  const int wr = w >> 1, wc = w & 1;
  const int lane16 = l & 15, g16 = l >> 4;
  const int r0 = blockIdx.y * BM;
  const int c0 = blockIdx.x * BN;

  f32x4 acc[4][4];
#pragma unroll
  for (int mi = 0; mi < 4; mi++)
#pragma unroll
    for (int nj = 0; nj < 4; nj++) acc[mi][nj] = (f32x4){0.f, 0.f, 0.f, 0.f};

  const char* qbase = (const char*)Q2h + (size_t)r0 * 1024;
  const char* gbase = (const char*)G2h + (size_t)c0 * 1024;

  // staging: linear LDS dest li[s]; pre-swizzled global source.
  // swizzle: byte ^= ((row&7)<<4), row = byte>>7 (128B rows) — involution.
  int li[4], rc[4];
#pragma unroll
  for (int s = 0; s < 4; s++) {
    li[s] = t * 16 + s * 4096;
    const int aa = li[s] ^ (((li[s] >> 7) & 7) << 4);
    rc[s] = (aa >> 7) * 1024 + (aa & 127);   // global row byte-offset + col
  }

  // fragment read offsets (swizzled). kk=1 is logical +64 (bit 6): since the
  // swizzle XOR covers bits 4-6, f(a+64) = f(a) ^ 64 (XOR, not add).
  int offA[4], offA2[4], offB[4], offB2[4];
#pragma unroll
  for (int i = 0; i < 4; i++) {
    const int a = (wr * 64 + i * 16 + lane16) * 128 + g16 * 16;
    offA[i] = a ^ (((a >> 7) & 7) << 4);
    offA2[i] = offA[i] ^ 64;
    const int b = (wc * 64 + i * 16 + lane16) * 128 + g16 * 16;
    offB[i] = b ^ (((b >> 7) & 7) << 4);
    offB2[i] = offB[i] ^ 64;
  }

#define GLDS(SRC, DOFF) __builtin_amdgcn_global_load_lds(GLPTR(SRC), LDSPTR(lds + (DOFF)), 16, 0, 0)

#pragma unroll 1
  for (int ks = 0; ks < NKS; ks++) {
    const int koff = ks * 128;
    __syncthreads();
#pragma unroll
    for (int s = 0; s < 4; s++) {
      GLDS(qbase + rc[s] + koff, li[s]);
      GLDS(gbase + rc[s] + koff, 16384 + li[s]);
    }
    __syncthreads();

    f16x8 av[4][2], bv[4][2];
#pragma unroll
    for (int i = 0; i < 4; i++) {
      av[i][0] = *(const f16x8*)(lds + offA[i]);
      av[i][1] = *(const f16x8*)(lds + offA2[i]);
      bv[i][0] = *(const f16x8*)(lds + 16384 + offB[i]);
      bv[i][1] = *(const f16x8*)(lds + 16384 + offB2[i]);
    }
#pragma unroll
    for (int kk = 0; kk < 2; kk++)
#pragma unroll
      for (int nj = 0; nj < 4; nj++)
#pragma unroll
        for (int mi = 0; mi < 4; mi++)
          acc[mi][nj] = __builtin_amdgcn_mfma_f32_16x16x32_f16(av[mi][kk], bv[nj][kk], acc[mi][nj], 0, 0, 0);
  }
#undef GLDS
  __syncthreads();

  // epilogue partial arrays overlaid on LDS
  uint32_t* pKey = (uint32_t*)lds;
  uint32_t* pC   = pKey + 256;
  float*    pD   = (float*)(pC + 256);
  float*    pM   = pD + 256;
  uint32_t* pMC  = (uint32_t*)(pM + 256);

  // distance + per-row reductions (acc = r, unscaled)
#pragma unroll
  for (int mi = 0; mi < 4; mi++) {
#pragma unroll
    for (int q = 0; q < 4; q++) {
      const int rr = wr * 64 + mi * 16 + g16 * 4 + q;
      const int r = r0 + rr;
      const float nqv = nqd[r];
      const float thr = psd[r] + 1e-4f;
      const int rg = r >> NIMG_SHIFT;
      uint32_t bKey = 0u, bC = 0xFFFFFFFFu, mC = 0xFFFFFFFFu;
      float bD = 0.0f, mD = INFINITY;
#pragma unroll
      for (int nj = 0; nj < 4; nj++) {
        const int c = c0 + wc * 64 + nj * 16 + lane16;
        const float dv = fmaxf(nqv + ngd[c] - 2.0f * acc[mi][nj][q], 1e-8f);
        const float dn = ((c >> NIMG_SHIFT) == rg) ? 1e25f : dv;
        if (dn < mD || (dn == mD && (uint32_t)c < mC)) { mD = dn; mC = (uint32_t)c; }
        if (dn < thr) {
          const uint32_t bits = draw_bits(kn0, kn1, (uint32_t)(r * B + c));
          const uint32_t key = (bits >> 9) + 1u;
          if (key > bKey || (key == bKey && (uint32_t)c < bC)) { bKey = key; bC = (uint32_t)c; bD = dn; }
        }
      }
#pragma unroll
      for (int off = 8; off >= 1; off >>= 1) {
        const uint32_t kO = __shfl_xor(bKey, off, 64);
        const uint32_t cO = __shfl_xor(bC, off, 64);
        const float dO = __shfl_xor(bD, off, 64);
        if (kO > bKey || (kO == bKey && cO < bC)) { bKey = kO; bC = cO; bD = dO; }
        const float mdO = __shfl_xor(mD, off, 64);
        const uint32_t mcO = __shfl_xor(mC, off, 64);
        if (mdO < mD || (mdO == mD && mcO < mC)) { mD = mdO; mC = mcO; }
      }
      if (lane16 == 0) {
        const int idx = wc * 128 + rr;
        pKey[idx] = bKey; pC[idx] = bC; pD[idx] = bD; pM[idx] = mD; pMC[idx] = mC;
      }
    }
  }
  __syncthreads();
  if (t < 128) {
    const int i0 = t, i1 = t + 128;
    const uint32_t k0 = pKey[i0], k1 = pKey[i1];
    const uint32_t c0v = pC[i0], c1v = pC[i1];
    const float d0 = pD[i0], d1 = pD[i1];
    uint32_t bk; float bd;
    if (k1 > k0 || (k1 == k0 && k1 != 0u && c1v < c0v)) { bk = k1; bd = d1; }
    else { bk = k0; bd = d0; }
    const float m0 = pM[i0], m1 = pM[i1];
    const uint32_t mc0 = pMC[i0], mc1 = pMC[i1];
    const float md = (m1 < m0 || (m1 == m0 && mc1 < mc0)) ? m1 : m0;
    const int p = (r0 + t) * NCH + blockIdx.x;
    bKeyd[p] = bk; bDnd[p] = bd; mDnd[p] = md;
  }
}

// ---------------- Kernel 4a: per-row chunk combine + softplus, block partial --
__global__ __launch_bounds__(256) void fin1_k() {
  __shared__ float red[8];
  const int t = threadIdx.x;
  const int lrow = t >> 5;              // 0..7 rows per block
  const int ch = t & 31;                // chunk index (NCH=32)
  const int r = blockIdx.x * 8 + lrow;
  const int p = r * NCH + ch;
  uint32_t bk = bKeyd[p];
  uint32_t bch = (uint32_t)ch;
  float bd = bDnd[p];
  float md = mDnd[p];
  uint32_t mch = (uint32_t)ch;
#pragma unroll
  for (int off = 16; off >= 1; off >>= 1) {
    const uint32_t kO = __shfl_xor(bk, off, 64);
    const uint32_t cO = __shfl_xor(bch, off, 64);
    const float dO = __shfl_xor(bd, off, 64);
    if (kO > bk || (kO == bk && cO < bch)) { bk = kO; bch = cO; bd = dO; }
    const float mO = __shfl_xor(md, off, 64);
    const uint32_t mcO = __shfl_xor(mch, off, 64);
    if (mO < md || (mO == md && mcO < mch)) { md = mO; mch = mcO; }
  }
  if (ch == 0) {
    const float dn = (bk != 0u) ? bd : md;
    const float x = 1e-4f + spd[r] - sqrtf(dn);
    red[lrow] = fmaxf(x, 0.0f) + log1pf(expf(-fabsf(x)));
  }
  __syncthreads();
  if (t == 0) {
    float s = 0.0f;
#pragma unroll
    for (int i = 0; i < 8; i++) s += red[i];
    partd[blockIdx.x] = s;
  }
}

// ---------------- Kernel 4b: sum 512 partials, mean ----------------
__global__ __launch_bounds__(256) void fin2_k(float* __restrict__ out) {
  __shared__ float red[256];
  const int t = threadIdx.x;
  red[t] = partd[t] + partd[t + 256];
  __syncthreads();
#pragma unroll
  for (int s = 128; s; s >>= 1) {
    if (t < s) red[t] += red[t + s];
    __syncthreads();
  }
  if (t == 0) out[0] = red[0] * (1.0f / (float)B);
}

extern "C" void kernel_launch(void* const* d_in, const int* in_sizes, int n_in,
                              void* d_out, int out_size, void* d_ws, size_t ws_size,
                              hipStream_t stream) {
  (void)in_sizes; (void)n_in; (void)out_size; (void)d_ws; (void)ws_size;
  const float* Q = (const float*)d_in[0];
  const float* G = (const float*)d_in[1];
  float* out = (float*)d_out;

  uint32_t kp0, kp1, kn0, kn1;
  tf2x32(0u, 42u, 0u, 0u, kp0, kp1);
  tf2x32(0u, 42u, 0u, 1u, kn0, kn1);

  hipLaunchKernelGGL(cvtn_k, dim3(2 * B / 4), dim3(256), 0, stream, Q, G);
  hipLaunchKernelGGL(pos_k, dim3(B / 8), dim3(256), 0, stream, Q, G, kp0, kp1);
  hipLaunchKernelGGL(neg_k, dim3(B / BN, B / BM), dim3(256), 0, stream, kn0, kn1);
  hipLaunchKernelGGL(fin1_k, dim3(B / 8), dim3(256), 0, stream);
  hipLaunchKernelGGL(fin2_k, dim3(1), dim3(256), 0, stream, out);
}